// Round 5
// baseline (79.648 us; speedup 1.0000x reference)
//
#include <hip/hip_runtime.h>

// Bilinear warp: out[b,c,h,w] = bilerp(img[b,c], (w+flo[b,0,h,w], h+flo[b,1,h,w]))
// img: [8,16,512,512] f32, flo: [8,2,512,512] f32, out: [8,16,512,512] f32.
//
// Round 5: vmcnt retires IN ISSUE ORDER and counts stores too -> in R4 every
// channel's gather-wait also waited on the previous channel's NT store ack.
// Fix: accumulate all 16 channel results in registers; ALL loads precede ALL
// stores, so gather waits never include store-acks. Keep merged-f2u gathers,
// 4px/thread, XCD-batch swizzle, NT stores (drain at kernel end), depth-4
// load pipeline. flo loads now regular (L3-cached across replays).

#define BB 8
#define CC 16
#define HH 512
#define WW 512
#define HWSZ (HH * WW)

#define TILE_W 256              // pixels per block in x (64 lanes * 4 px)
#define TILE_H 4                // rows per block
#define TILES_X (WW / TILE_W)   // 2
#define TILES_Y (HH / TILE_H)   // 128
#define TILES_PER_IMG (TILES_X * TILES_Y)  // 256
#define NBLOCKS (BB * TILES_PER_IMG)       // 2048 (= 8 * 256, swizzle bijective)
#define NXCD 8

typedef float f2u __attribute__((ext_vector_type(2), aligned(4)));  // 4B-aligned pair
typedef float f4  __attribute__((ext_vector_type(4)));

__global__ __launch_bounds__(256, 1) void warp_bilinear_kernel(
    const float* __restrict__ img,
    const float* __restrict__ flo,
    float* __restrict__ out)
{
    // XCD swizzle: XCD k <- batch k, tiles top-to-bottom (2048 = 8*256).
    int bid = blockIdx.x;
    int wk  = (bid % NXCD) * (NBLOCKS / NXCD) + bid / NXCD;

    int b    = wk / TILES_PER_IMG;
    int tile = wk - b * TILES_PER_IMG;
    int ty   = tile / TILES_X;
    int tx   = tile - ty * TILES_X;

    int lane = threadIdx.x & 63;     // wave = one row of 256 px
    int row  = threadIdx.x >> 6;
    int h    = ty * TILE_H + row;
    int w0   = tx * TILE_W + lane * 4;
    int hw   = h * WW + w0;

    // flow: 16B-aligned float4 loads (regular: L3-resident across replays)
    f4 fx4 = *(const f4*)(flo + (size_t)(b * 2 + 0) * HWSZ + hw);
    f4 fy4 = *(const f4*)(flo + (size_t)(b * 2 + 1) * HWSZ + hw);

    // Per-pixel precompute: merged-pair base offsets + boundary-folded weights.
    // x1 in {x0, x0+1}; load float2 at xb=min(x0,W-2) so both corners are in it.
    int   ib0[4], ib1[4];
    float wtx[4], wty[4], wbx[4], wby[4];
    #pragma unroll
    for (int i = 0; i < 4; ++i) {
        float pos_x = (float)(w0 + i) + fx4[i];
        float pos_y = (float)h + fy4[i];

        float x0f = floorf(pos_x);
        float y0f = floorf(pos_y);
        float xw  = pos_x - x0f;     // weights from UNclamped floor (reference)
        float yw  = pos_y - y0f;

        int x0 = (int)fminf(fmaxf(x0f,        0.0f), (float)(WW - 1));
        int x1 = (int)fminf(fmaxf(x0f + 1.0f, 0.0f), (float)(WW - 1));
        int y0 = (int)fminf(fmaxf(y0f,        0.0f), (float)(HH - 1));
        int y1 = (int)fminf(fmaxf(y0f + 1.0f, 0.0f), (float)(HH - 1));

        int xb = min(x0, WW - 2);    // float2 window [xb, xb+1], never OOB

        float wa = (1.0f - xw) * (1.0f - yw);
        float wb = (1.0f - xw) * yw;
        float wc = xw * (1.0f - yw);
        float wd = xw * yw;

        float tx_ = (x0 == xb ? wa : 0.0f) + (x1 == xb ? wc : 0.0f);
        float bx_ = (x0 == xb ? wb : 0.0f) + (x1 == xb ? wd : 0.0f);
        wtx[i] = tx_;  wty[i] = (wa + wc) - tx_;
        wbx[i] = bx_;  wby[i] = (wb + wd) - bx_;

        ib0[i] = y0 * WW + xb;
        ib1[i] = y1 * WW + xb;
    }

    const float* imgb = img + (size_t)b * CC * HWSZ;
    float*       outb = out + (size_t)b * CC * HWSZ;

    // Depth-4 load pipeline; results accumulate in registers, stores at end.
    auto loadc = [&](f2u (&t)[4], f2u (&bo)[4], int c) {
        const float* p = imgb + (size_t)c * HWSZ;
        #pragma unroll
        for (int i = 0; i < 4; ++i) {
            t[i]  = *(const f2u*)(p + ib0[i]);   // (y0, xb..xb+1)
            bo[i] = *(const f2u*)(p + ib1[i]);   // (y1, xb..xb+1)
        }
    };
    auto comp = [&](const f2u (&t)[4], const f2u (&bo)[4]) -> f4 {
        f4 v;
        #pragma unroll
        for (int i = 0; i < 4; ++i)
            v[i] = wtx[i] * t[i].x + wty[i] * t[i].y
                 + wbx[i] * bo[i].x + wby[i] * bo[i].y;
        return v;
    };

    f2u At[4], Ab[4], Bt[4], Bb[4], Ct[4], Cb[4], Dt[4], Db[4];
    f4  o0,o1,o2,o3,o4,o5,o6,o7,o8,o9,o10,o11,o12,o13,o14,o15;

    loadc(At, Ab, 0);
    loadc(Bt, Bb, 1);
    loadc(Ct, Cb, 2);
    loadc(Dt, Db, 3);

    o0  = comp(At, Ab);   loadc(At, Ab, 4);
    o1  = comp(Bt, Bb);   loadc(Bt, Bb, 5);
    o2  = comp(Ct, Cb);   loadc(Ct, Cb, 6);
    o3  = comp(Dt, Db);   loadc(Dt, Db, 7);

    o4  = comp(At, Ab);   loadc(At, Ab, 8);
    o5  = comp(Bt, Bb);   loadc(Bt, Bb, 9);
    o6  = comp(Ct, Cb);   loadc(Ct, Cb, 10);
    o7  = comp(Dt, Db);   loadc(Dt, Db, 11);

    o8  = comp(At, Ab);   loadc(At, Ab, 12);
    o9  = comp(Bt, Bb);   loadc(Bt, Bb, 13);
    o10 = comp(Ct, Cb);   loadc(Ct, Cb, 14);
    o11 = comp(Dt, Db);   loadc(Dt, Db, 15);

    o12 = comp(At, Ab);
    o13 = comp(Bt, Bb);
    o14 = comp(Ct, Cb);
    o15 = comp(Dt, Db);

    // All stores AFTER all loads: no gather-wait ever includes a store-ack.
    // NT: out is never re-read; keep L2/L3 for img.
    __builtin_nontemporal_store(o0,  (f4*)(outb + (size_t) 0 * HWSZ + hw));
    __builtin_nontemporal_store(o1,  (f4*)(outb + (size_t) 1 * HWSZ + hw));
    __builtin_nontemporal_store(o2,  (f4*)(outb + (size_t) 2 * HWSZ + hw));
    __builtin_nontemporal_store(o3,  (f4*)(outb + (size_t) 3 * HWSZ + hw));
    __builtin_nontemporal_store(o4,  (f4*)(outb + (size_t) 4 * HWSZ + hw));
    __builtin_nontemporal_store(o5,  (f4*)(outb + (size_t) 5 * HWSZ + hw));
    __builtin_nontemporal_store(o6,  (f4*)(outb + (size_t) 6 * HWSZ + hw));
    __builtin_nontemporal_store(o7,  (f4*)(outb + (size_t) 7 * HWSZ + hw));
    __builtin_nontemporal_store(o8,  (f4*)(outb + (size_t) 8 * HWSZ + hw));
    __builtin_nontemporal_store(o9,  (f4*)(outb + (size_t) 9 * HWSZ + hw));
    __builtin_nontemporal_store(o10, (f4*)(outb + (size_t)10 * HWSZ + hw));
    __builtin_nontemporal_store(o11, (f4*)(outb + (size_t)11 * HWSZ + hw));
    __builtin_nontemporal_store(o12, (f4*)(outb + (size_t)12 * HWSZ + hw));
    __builtin_nontemporal_store(o13, (f4*)(outb + (size_t)13 * HWSZ + hw));
    __builtin_nontemporal_store(o14, (f4*)(outb + (size_t)14 * HWSZ + hw));
    __builtin_nontemporal_store(o15, (f4*)(outb + (size_t)15 * HWSZ + hw));
}

extern "C" void kernel_launch(void* const* d_in, const int* in_sizes, int n_in,
                              void* d_out, int out_size, void* d_ws, size_t ws_size,
                              hipStream_t stream)
{
    const float* img = (const float*)d_in[0];
    const float* flo = (const float*)d_in[1];
    float*       out = (float*)d_out;

    warp_bilinear_kernel<<<NBLOCKS, 256, 0, stream>>>(img, flo, out);
}

// Round 6
// 75.776 us; speedup vs baseline: 1.0511x; 1.0511x over previous
//
#include <hip/hip_runtime.h>

// Bilinear warp: out[b,c,h,w] = bilerp(img[b,c], (w+flo[b,0,h,w], h+flo[b,1,h,w]))
// img: [8,16,512,512] f32, flo: [8,2,512,512] f32, out: [8,16,512,512] f32.
//
// Round 6: R4 structure (best, 66us) with ONE change: pixel->lane mapping.
// R4: lane owns 4 consecutive px -> each gather instr spans ~1KB -> ~17
// L1 line-transactions per instruction (TCP serializes distinct lines).
// Now: lane l owns px {l, l+64, l+128, l+192} -> each gather instr has
// 4B-stride lane addresses (+-flow jitter) -> ~5-6 lines/instr, ~3x fewer
// TCP transactions. Stores become 4 coalesced dword stores per channel
// (same line count as one f4 store). Keep XCD-batch swizzle, merged-f2u
// corner gathers, NT stores right after each channel's compute, depth-4
// channel pipeline with named buffers.

#define BB 8
#define CC 16
#define HH 512
#define WW 512
#define HWSZ (HH * WW)

#define TILE_W 256              // px per block in x (one wave per row, 4 px/lane strided)
#define TILE_H 4                // rows per block (4 waves)
#define TILES_X (WW / TILE_W)   // 2
#define TILES_Y (HH / TILE_H)   // 128
#define TILES_PER_IMG (TILES_X * TILES_Y)  // 256
#define NBLOCKS (BB * TILES_PER_IMG)       // 2048 (= 8 * 256, swizzle bijective)
#define NXCD 8

typedef float f2u __attribute__((ext_vector_type(2), aligned(4)));  // 4B-aligned pair

__global__ __launch_bounds__(256) void warp_bilinear_kernel(
    const float* __restrict__ img,
    const float* __restrict__ flo,
    float* __restrict__ out)
{
    // XCD swizzle: XCD k <- batch k, tiles top-to-bottom (2048 = 8*256).
    int bid = blockIdx.x;
    int wk  = (bid % NXCD) * (NBLOCKS / NXCD) + bid / NXCD;

    int b    = wk / TILES_PER_IMG;
    int tile = wk - b * TILES_PER_IMG;
    int ty   = tile / TILES_X;
    int tx   = tile - ty * TILES_X;

    int lane = threadIdx.x & 63;     // wave = one row of 256 px
    int row  = threadIdx.x >> 6;
    int h    = ty * TILE_H + row;
    int wbase = tx * TILE_W + lane;  // this thread's px: wbase + 64*i, i=0..3
    int hwb   = h * WW + wbase;

    const float* flox = flo + (size_t)(b * 2 + 0) * HWSZ + hwb;
    const float* floy = flo + (size_t)(b * 2 + 1) * HWSZ + hwb;

    // Per-pixel precompute: merged-pair base offsets + boundary-folded weights.
    // x1 in {x0, x0+1}; load float2 at xb=min(x0,W-2) so both corners are in it.
    int   ib0[4], ib1[4];
    float wtx[4], wty[4], wbx[4], wby[4];
    #pragma unroll
    for (int i = 0; i < 4; ++i) {
        float fx = flox[64 * i];     // coalesced: lanes contiguous
        float fy = floy[64 * i];

        float pos_x = (float)(wbase + 64 * i) + fx;
        float pos_y = (float)h + fy;

        float x0f = floorf(pos_x);
        float y0f = floorf(pos_y);
        float xw  = pos_x - x0f;     // weights from UNclamped floor (reference)
        float yw  = pos_y - y0f;

        int x0 = (int)fminf(fmaxf(x0f,        0.0f), (float)(WW - 1));
        int x1 = (int)fminf(fmaxf(x0f + 1.0f, 0.0f), (float)(WW - 1));
        int y0 = (int)fminf(fmaxf(y0f,        0.0f), (float)(HH - 1));
        int y1 = (int)fminf(fmaxf(y0f + 1.0f, 0.0f), (float)(HH - 1));

        int xb = min(x0, WW - 2);    // float2 window [xb, xb+1], never OOB

        float wa = (1.0f - xw) * (1.0f - yw);
        float wb = (1.0f - xw) * yw;
        float wc = xw * (1.0f - yw);
        float wd = xw * yw;

        float tx_ = (x0 == xb ? wa : 0.0f) + (x1 == xb ? wc : 0.0f);
        float bx_ = (x0 == xb ? wb : 0.0f) + (x1 == xb ? wd : 0.0f);
        wtx[i] = tx_;  wty[i] = (wa + wc) - tx_;
        wbx[i] = bx_;  wby[i] = (wb + wd) - bx_;

        ib0[i] = y0 * WW + xb;
        ib1[i] = y1 * WW + xb;
    }

    const float* imgb = img + (size_t)b * CC * HWSZ;
    float*       outb = out + (size_t)b * CC * HWSZ;

    // Depth-4 channel pipeline, named buffers (compile-time indices only).
    auto loadc = [&](f2u (&t)[4], f2u (&bo)[4], int c) {
        const float* p = imgb + (size_t)c * HWSZ;
        #pragma unroll
        for (int i = 0; i < 4; ++i) {
            t[i]  = *(const f2u*)(p + ib0[i]);   // (y0, xb..xb+1) — lanes ~contiguous
            bo[i] = *(const f2u*)(p + ib1[i]);   // (y1, xb..xb+1)
        }
    };
    auto comp = [&](const f2u (&t)[4], const f2u (&bo)[4], int c) {
        float* po = outb + (size_t)c * HWSZ + hwb;
        #pragma unroll
        for (int i = 0; i < 4; ++i) {
            float v = wtx[i] * t[i].x + wty[i] * t[i].y
                    + wbx[i] * bo[i].x + wby[i] * bo[i].y;
            // coalesced dword store (lanes contiguous); NT: out never re-read
            __builtin_nontemporal_store(v, po + 64 * i);
        }
    };

    f2u At[4], Ab[4], Bt[4], Bb[4], Ct[4], Cb[4], Dt[4], Db[4];

    loadc(At, Ab, 0);
    loadc(Bt, Bb, 1);
    loadc(Ct, Cb, 2);
    loadc(Dt, Db, 3);

    comp(At, Ab, 0);   loadc(At, Ab, 4);
    comp(Bt, Bb, 1);   loadc(Bt, Bb, 5);
    comp(Ct, Cb, 2);   loadc(Ct, Cb, 6);
    comp(Dt, Db, 3);   loadc(Dt, Db, 7);

    comp(At, Ab, 4);   loadc(At, Ab, 8);
    comp(Bt, Bb, 5);   loadc(Bt, Bb, 9);
    comp(Ct, Cb, 6);   loadc(Ct, Cb, 10);
    comp(Dt, Db, 7);   loadc(Dt, Db, 11);

    comp(At, Ab, 8);   loadc(At, Ab, 12);
    comp(Bt, Bb, 9);   loadc(Bt, Bb, 13);
    comp(Ct, Cb, 10);  loadc(Ct, Cb, 14);
    comp(Dt, Db, 11);  loadc(Dt, Db, 15);

    comp(At, Ab, 12);
    comp(Bt, Bb, 13);
    comp(Ct, Cb, 14);
    comp(Dt, Db, 15);
}

extern "C" void kernel_launch(void* const* d_in, const int* in_sizes, int n_in,
                              void* d_out, int out_size, void* d_ws, size_t ws_size,
                              hipStream_t stream)
{
    const float* img = (const float*)d_in[0];
    const float* flo = (const float*)d_in[1];
    float*       out = (float*)d_out;

    warp_bilinear_kernel<<<NBLOCKS, 256, 0, stream>>>(img, flo, out);
}

// Round 7
// 50.583 us; speedup vs baseline: 1.5746x; 1.4981x over previous
//
#include <hip/hip_runtime.h>

// Bilinear warp: out[b,c,h,w] = bilerp(img[b,c], (w+flo[b,0,h,w], h+flo[b,1,h,w]))
// img: [8,16,512,512] f32, flo: [8,2,512,512] f32, out: [8,16,512,512] f32.
//
// Round 7: measured law: time ~= 39us + 22.7us per M wave-VMEM-instructions.
// R4 (66us) is at the global-gather instruction minimum (146/wave). Move the
// 128 gathers/wave to the DS pipe: stage a 33x84 halo window per channel in
// LDS via global_load_lds(16B) (3 VMEM/wave/ch), double-buffered with counted
// vmcnt (never drain to 0 mid-loop) + raw s_barrier. Gathers -> ds_read2_b32.
// VMEM/wave: 146 -> 66. Flow outside +-8 halo (prob ~1e-8, but data-dep):
// per-pixel fixup pass with global gathers guarantees correctness.

#define BB 8
#define CC 16
#define HH 512
#define WW 512
#define HWSZ (HH * WW)

#define TW 64                    // output tile width
#define TH 16                    // output tile height
#define TILES_X (WW / TW)        // 8
#define TILES_Y (HH / TH)        // 32
#define TPI (TILES_X * TILES_Y)  // 256
#define NBLOCKS (BB * TPI)       // 2048 = 8 * 256 (XCD k <- batch k, bijective)
#define NXCD 8

#define HALO 8
#define WIN_COLS 84              // 64 + 20, = 21 float4 per row (never row-crossing)
#define WIN_ROWS 33              // 16 + 17
#define PAD_FLOATS 3072          // 12 chunks * 256 floats (covers 33*84=2772 + pad)
                                 // 3 chunks per wave, uniform across waves

typedef float f4 __attribute__((ext_vector_type(4)));

__device__ __forceinline__ void gload_lds16(const float* g, float* l) {
    // per-lane global src; wave-uniform LDS base, HW writes base + lane*16
    __builtin_amdgcn_global_load_lds(
        (const __attribute__((address_space(1))) void*)g,
        (__attribute__((address_space(3))) void*)l,
        16, 0, 0);
}

__global__ __launch_bounds__(256) void warp_bilinear_kernel(
    const float* __restrict__ img,
    const float* __restrict__ flo,
    float* __restrict__ out)
{
    __shared__ __align__(16) float lds[2 * PAD_FLOATS];

    // XCD swizzle: XCD k <- batch k, tiles top-to-bottom.
    int bid = blockIdx.x;
    int wk  = (bid % NXCD) * (NBLOCKS / NXCD) + bid / NXCD;
    int b    = wk / TPI;
    int tile = wk - b * TPI;
    int ty   = tile / TILES_X;
    int tx   = tile - ty * TILES_X;

    int t    = threadIdx.x;
    int wv   = t >> 6;               // wave id 0..3
    int lane = t & 63;

    int r   = t >> 4;                // row in tile 0..15
    int c4  = (t & 15) << 2;         // col in tile, 4 px per thread
    int h   = ty * TH + r;
    int w0  = tx * TW + c4;
    int hw  = h * WW + w0;
    int wx0 = tx * TW - HALO;        // staged window origin (may be <0)
    int wy0 = ty * TH - HALO;

    const float* imgb = img + (size_t)b * CC * HWSZ;
    float*       outb = out + (size_t)b * CC * HWSZ;

    // ---- staging chunk setup: wave wv stages chunks {wv, wv+4, wv+8} -------
    const float* srcp[3];            // per-lane global src, channel 0
    int          loff[3];            // LDS float offset (wave-uniform)
    #pragma unroll
    for (int j = 0; j < 3; ++j) {
        int k  = wv + 4 * j;
        int f  = k * 256 + lane * 4;           // float idx in window (mult of 4)
        int rr = f / 84;                        // window row (84 = 21*4, groups
        int cc = f - rr * 84;                   //  never straddle rows)
        int gy = min(max(wy0 + rr, 0), HH - 1); // clamp: pad/halo rows duplicate
        int gx = min(max(wx0 + cc, 0), WW - 4); //  edge data (only unread slots
        srcp[j] = imgb + gy * WW + gx;          //  differ from true window)
        loff[j] = k * 256;
    }

    auto stage = [&](int ch, int buf) {
        const size_t choff = (size_t)ch * HWSZ;
        float* lbase = lds + buf * PAD_FLOATS;
        #pragma unroll
        for (int j = 0; j < 3; ++j)
            gload_lds16(srcp[j] + choff, lbase + loff[j]);
    };

    stage(0, 0);   // get channel 0 in flight before any dependent work

    // ---- per-pixel precompute (overlaps stage(0) latency) ------------------
    f4 fx4 = *(const f4*)(flo + (size_t)(b * 2 + 0) * HWSZ + hw);
    f4 fy4 = *(const f4*)(flo + (size_t)(b * 2 + 1) * HWSZ + hw);

    int   o0[4], o1[4];
    float wtx[4], wty[4], wbx[4], wby[4];
    int   badmask = 0;
    #pragma unroll
    for (int i = 0; i < 4; ++i) {
        float pos_x = (float)(w0 + i) + fx4[i];
        float pos_y = (float)h + fy4[i];

        float x0f = floorf(pos_x);
        float y0f = floorf(pos_y);
        float xw  = pos_x - x0f;     // weights from UNclamped floor (reference)
        float yw  = pos_y - y0f;

        int x0 = (int)fminf(fmaxf(x0f,        0.0f), (float)(WW - 1));
        int x1 = (int)fminf(fmaxf(x0f + 1.0f, 0.0f), (float)(WW - 1));
        int y0 = (int)fminf(fmaxf(y0f,        0.0f), (float)(HH - 1));
        int y1 = (int)fminf(fmaxf(y0f + 1.0f, 0.0f), (float)(HH - 1));

        int xb = min(x0, WW - 2);    // merged pair [xb, xb+1]

        float wa = (1.0f - xw) * (1.0f - yw);
        float wb = (1.0f - xw) * yw;
        float wc = xw * (1.0f - yw);
        float wd = xw * yw;

        float tx_ = (x0 == xb ? wa : 0.0f) + (x1 == xb ? wc : 0.0f);
        float bx_ = (x0 == xb ? wb : 0.0f) + (x1 == xb ? wd : 0.0f);
        wtx[i] = tx_;  wty[i] = (wa + wc) - tx_;
        wbx[i] = bx_;  wby[i] = (wb + wd) - bx_;

        bool ok = (xb >= wx0) & (xb + 1 <= wx0 + WIN_COLS - 1)
                & (y0 >= wy0) & (y1 <= wy0 + WIN_ROWS - 1);
        int a0 = (y0 - wy0) * WIN_COLS + (xb - wx0);
        int a1 = (y1 - wy0) * WIN_COLS + (xb - wx0);
        if (!ok) { a0 = 0; a1 = 0; badmask |= (1 << i); }  // safe dummy; fixed up
        o0[i] = a0;  o1[i] = a1;
    }

    // ---- channel loop: stage(c+1) || compute(c), counted vmcnt -------------
    // issue order/wave: [stage0 x3][flo x2] | per iter: [stage(c+1) x3][store(c) x1]
    // c==0 : newest 3 = stage(1)            -> vmcnt(3) drains stage(0)+flo
    // 0<c<15: newest 4 = stage(c+1)+store(c-1... wait store(c-1)) -> vmcnt(4)
    //         drains stage(c) and all older stores; store stays in flight
    // c==15: newest 1 = store(14)           -> vmcnt(1) drains stage(15)
    #pragma unroll
    for (int c = 0; c < CC; ++c) {
        const int buf = c & 1;
        if (c < CC - 1) stage(c + 1, buf ^ 1);

        if (c == 0)          asm volatile("s_waitcnt vmcnt(3)" ::: "memory");
        else if (c < CC - 1) asm volatile("s_waitcnt vmcnt(4)" ::: "memory");
        else                 asm volatile("s_waitcnt vmcnt(1)" ::: "memory");
        __builtin_amdgcn_sched_barrier(0);
        __builtin_amdgcn_s_barrier();          // buf[c&1] staged, all waves

        const float* cur = lds + buf * PAD_FLOATS;
        f4 v;
        #pragma unroll
        for (int i = 0; i < 4; ++i) {
            float t0 = cur[o0[i]];
            float t1 = cur[o0[i] + 1];
            float u0 = cur[o1[i]];
            float u1 = cur[o1[i] + 1];
            v[i] = wtx[i] * t0 + wty[i] * t1 + wbx[i] * u0 + wby[i] * u1;
        }
        __builtin_nontemporal_store(v, (f4*)(outb + (size_t)c * HWSZ + hw));

        if (c < CC - 1) {
            asm volatile("s_waitcnt lgkmcnt(0)" ::: "memory"); // ds reads done
            __builtin_amdgcn_s_barrier();      // before buf is overwritten
        }
    }

    // ---- fixup: pixels whose footprint missed the staged window (~never) ---
    if (__builtin_expect(badmask != 0, 0)) {
        #pragma unroll
        for (int i = 0; i < 4; ++i) if (badmask & (1 << i)) {
            float fx = flo[(size_t)(b * 2 + 0) * HWSZ + hw + i];
            float fy = flo[(size_t)(b * 2 + 1) * HWSZ + hw + i];
            float pos_x = (float)(w0 + i) + fx;
            float pos_y = (float)h + fy;
            float x0f = floorf(pos_x), y0f = floorf(pos_y);
            float xw = pos_x - x0f,   yw = pos_y - y0f;
            int x0 = (int)fminf(fmaxf(x0f,        0.0f), (float)(WW - 1));
            int x1 = (int)fminf(fmaxf(x0f + 1.0f, 0.0f), (float)(WW - 1));
            int y0 = (int)fminf(fmaxf(y0f,        0.0f), (float)(HH - 1));
            int y1 = (int)fminf(fmaxf(y0f + 1.0f, 0.0f), (float)(HH - 1));
            float wa = (1.0f - xw) * (1.0f - yw);
            float wb = (1.0f - xw) * yw;
            float wc = xw * (1.0f - yw);
            float wd = xw * yw;
            for (int c = 0; c < CC; ++c) {
                const float* p = imgb + (size_t)c * HWSZ;
                float vv = wa * p[y0 * WW + x0] + wb * p[y1 * WW + x0]
                         + wc * p[y0 * WW + x1] + wd * p[y1 * WW + x1];
                outb[(size_t)c * HWSZ + hw + i] = vv;   // same thread: ordered
            }
        }
    }
}

extern "C" void kernel_launch(void* const* d_in, const int* in_sizes, int n_in,
                              void* d_out, int out_size, void* d_ws, size_t ws_size,
                              hipStream_t stream)
{
    const float* img = (const float*)d_in[0];
    const float* flo = (const float*)d_in[1];
    float*       out = (float*)d_out;

    warp_bilinear_kernel<<<NBLOCKS, 256, 0, stream>>>(img, flo, out);
}